// Round 9
// baseline (273.395 us; speedup 1.0000x reference)
//
#include <hip/hip_runtime.h>

#define PP 399
#define BB 256

// ---------------------------------------------------------------------------
// DUAL-STREAM streaming conv+relu+maxpool state machines (per p, two b rows).
// Weights/bias/control shared across the two streams; xw/pool state per-stream.
// Window j covers conv outputs [3j, 3j+9]; emitted when conv t=3j+9 arrives.
// feed computes conv t = nin-2. Mid-start: preload xw (STATIC slots) + nin.
// Rule #20: never runtime-index xw/state arrays (round-6 scratch disaster).
// ---------------------------------------------------------------------------
struct S1D {
    float w[3][5]; float b[3];
    float xw[2][5];
    float m1[2][3], m2[2][3], m3[2][3];
    int nin;
};
struct S3D {
    float w[3][3][5]; float b[3];
    float xw[2][3][5];
    float m1[2][3], m2[2][3], m3[2][3];
    int nin;
};

__device__ __forceinline__ void init_s1d(S1D& s, const float* __restrict__ Wt,
                                         const float* __restrict__ Bs, int p) {
    const float* wp = Wt + (long)p * 15;   // W1: [P][3][1][5]
#pragma unroll
    for (int co = 0; co < 3; ++co)
#pragma unroll
        for (int k = 0; k < 5; ++k) s.w[co][k] = wp[co * 5 + k];
#pragma unroll
    for (int co = 0; co < 3; ++co) s.b[co] = Bs[(long)p * 3 + co];
#pragma unroll
    for (int st = 0; st < 2; ++st) {
#pragma unroll
        for (int k = 0; k < 5; ++k) s.xw[st][k] = 0.f;
#pragma unroll
        for (int co = 0; co < 3; ++co) { s.m1[st][co] = -1e30f; s.m2[st][co] = -1e30f; s.m3[st][co] = -1e30f; }
    }
    s.nin = 0;
}

__device__ __forceinline__ void init_s3d(S3D& s, const float* __restrict__ Wt,
                                         const float* __restrict__ Bs, int p) {
    const float* wp = Wt + (long)p * 45;   // W2/3/4: [P][3][3][5]
#pragma unroll
    for (int co = 0; co < 3; ++co)
#pragma unroll
        for (int ci = 0; ci < 3; ++ci)
#pragma unroll
            for (int k = 0; k < 5; ++k)
                s.w[co][ci][k] = wp[(co * 3 + ci) * 5 + k];
#pragma unroll
    for (int co = 0; co < 3; ++co) s.b[co] = Bs[(long)p * 3 + co];
#pragma unroll
    for (int st = 0; st < 2; ++st) {
#pragma unroll
        for (int ci = 0; ci < 3; ++ci)
#pragma unroll
            for (int k = 0; k < 5; ++k) s.xw[st][ci][k] = 0.f;
#pragma unroll
        for (int co = 0; co < 3; ++co) { s.m1[st][co] = -1e30f; s.m2[st][co] = -1e30f; s.m3[st][co] = -1e30f; }
    }
    s.nin = 0;
}

__device__ __forceinline__ bool feed1(S1D& s, const float (&in)[2], float (&out)[2][3]) {
#pragma unroll
    for (int st = 0; st < 2; ++st) {
        s.xw[st][0] = s.xw[st][1];
        s.xw[st][1] = s.xw[st][2];
        s.xw[st][2] = s.xw[st][3];
        s.xw[st][3] = s.xw[st][4];
        s.xw[st][4] = in[st];
    }
    int t = s.nin - 2;
    s.nin++;
    if (t < 0) return false;

    float c[2][3];
#pragma unroll
    for (int st = 0; st < 2; ++st)
#pragma unroll
        for (int co = 0; co < 3; ++co) {
            float a = s.b[co];
#pragma unroll
            for (int k = 0; k < 5; ++k)
                a = fmaf(s.xw[st][k], s.w[co][k], a);
            c[st][co] = fmaxf(a, 0.f);
        }

    bool emit = false;
    int ph = t % 3;
    if (ph == 0) {
        if (t >= 9) {
#pragma unroll
            for (int st = 0; st < 2; ++st)
#pragma unroll
                for (int co = 0; co < 3; ++co)
                    out[st][co] = fmaxf(s.m1[st][co], c[st][co]);
            emit = true;
        }
#pragma unroll
        for (int st = 0; st < 2; ++st)
#pragma unroll
            for (int co = 0; co < 3; ++co) {
                float a = fmaxf(s.m2[st][co], c[st][co]);
                float bb = fmaxf(s.m3[st][co], c[st][co]);
                s.m1[st][co] = a; s.m2[st][co] = bb; s.m3[st][co] = c[st][co];
            }
    } else {
#pragma unroll
        for (int st = 0; st < 2; ++st)
#pragma unroll
            for (int co = 0; co < 3; ++co) {
                s.m1[st][co] = fmaxf(s.m1[st][co], c[st][co]);
                s.m2[st][co] = fmaxf(s.m2[st][co], c[st][co]);
                s.m3[st][co] = fmaxf(s.m3[st][co], c[st][co]);
            }
    }
    return emit;
}

__device__ __forceinline__ bool feed3(S3D& s, const float (&in)[2][3], float (&out)[2][3]) {
#pragma unroll
    for (int st = 0; st < 2; ++st)
#pragma unroll
        for (int ci = 0; ci < 3; ++ci) {
            s.xw[st][ci][0] = s.xw[st][ci][1];
            s.xw[st][ci][1] = s.xw[st][ci][2];
            s.xw[st][ci][2] = s.xw[st][ci][3];
            s.xw[st][ci][3] = s.xw[st][ci][4];
            s.xw[st][ci][4] = in[st][ci];
        }
    int t = s.nin - 2;
    s.nin++;
    if (t < 0) return false;

    float c[2][3];
#pragma unroll
    for (int st = 0; st < 2; ++st)
#pragma unroll
        for (int co = 0; co < 3; ++co) {
            float a = s.b[co];
#pragma unroll
            for (int ci = 0; ci < 3; ++ci)
#pragma unroll
                for (int k = 0; k < 5; ++k)
                    a = fmaf(s.xw[st][ci][k], s.w[co][ci][k], a);
            c[st][co] = fmaxf(a, 0.f);
        }

    bool emit = false;
    int ph = t % 3;
    if (ph == 0) {
        if (t >= 9) {
#pragma unroll
            for (int st = 0; st < 2; ++st)
#pragma unroll
                for (int co = 0; co < 3; ++co)
                    out[st][co] = fmaxf(s.m1[st][co], c[st][co]);
            emit = true;
        }
#pragma unroll
        for (int st = 0; st < 2; ++st)
#pragma unroll
            for (int co = 0; co < 3; ++co) {
                float a = fmaxf(s.m2[st][co], c[st][co]);
                float bb = fmaxf(s.m3[st][co], c[st][co]);
                s.m1[st][co] = a; s.m2[st][co] = bb; s.m3[st][co] = c[st][co];
            }
    } else {
#pragma unroll
        for (int st = 0; st < 2; ++st)
#pragma unroll
            for (int co = 0; co < 3; ++co) {
                s.m1[st][co] = fmaxf(s.m1[st][co], c[st][co]);
                s.m2[st][co] = fmaxf(s.m2[st][co], c[st][co]);
                s.m3[st][co] = fmaxf(s.m3[st][co], c[st][co]);
            }
    }
    return emit;
}

__device__ __forceinline__ void pump12(S1D& s1, S3D& s2, const float (&xv)[2],
                                       int& oc, int j0,
                                       float* __restrict__ o20, float* __restrict__ o21)
{
    float v1[2][3], v2[2][3];
    if (feed1(s1, xv, v1)) {
        if (feed3(s2, v1, v2)) {
            int j = j0 + oc;
            oc++;
#pragma unroll
            for (int co = 0; co < 3; ++co) {
                o20[(long)(co * 37 + j) * PP] = v2[0][co];
                o21[(long)(co * 37 + j) * PP] = v2[1][co];
            }
        }
    }
}

// ---------------------------------------------------------------------------
// Fused stage1+stage2, 3-way T-segmented, dual-b-stream:
// x [256][365][399] -> h2 [256][3][37][399]. Thread = (b, b+128) at one p.
// ---------------------------------------------------------------------------
__global__ __launch_bounds__(64, 2)
void conv_s12_seg(const float* __restrict__ x,
                  const float* __restrict__ W1, const float* __restrict__ b1,
                  const float* __restrict__ W2, const float* __restrict__ b2,
                  float* __restrict__ h2)
{
    int gid = blockIdx.x * 64 + threadIdx.x;
    if (gid >= (BB / 2) * PP) return;
    int b = gid / PP;               // 0..127
    int p = gid - b * PP;

    int seg = blockIdx.y;
    int j0 = (seg == 0) ? 0 : ((seg == 1) ? 13 : 25);
    int j1 = (seg == 0) ? 13 : ((seg == 1) ? 25 : 37);
    int npz    = (seg == 0) ? 2 : 0;
    int Istart = (seg == 0) ? 0 : (3 * j0 - 2);
    int Iend   = min(3 * j1 + 8, 118);
    int T0 = 3 * Istart;

    S1D s1; S3D s2;
    init_s1d(s1, W1, b1, p);
    init_s3d(s2, W2, b2, p);

    const float* inp0 = x + (long)b * 365 * PP + p;
    const float* inp1 = x + (long)(b + 128) * 365 * PP + p;
    float* o20 = h2 + (long)b * (3 * 37 * PP) + p;
    float* o21 = h2 + (long)(b + 128) * (3 * 37 * PP) + p;

    // s1 mid-start: xw[st][1..4] = x[T0-2 .. T0+1] (STATIC slot indices)
#pragma unroll
    for (int k = 0; k < 4; ++k) {
        int t = T0 - 2 + k;
        bool ok = (t >= 0 && t < 365);
        s1.xw[0][1 + k] = ok ? inp0[(long)t * PP] : 0.f;
        s1.xw[1][1 + k] = ok ? inp1[(long)t * PP] : 0.f;
    }
    s1.nin = 2;
    s2.nin = npz - 2;

    int oc = 0;
    int nfeed = 3 * (Iend - Istart) + 10;   // == 1 (mod 3)
    int NG = nfeed / 3;
    int ibase = T0 + 2;

    float cur[3][2], nxt[3][2];
#pragma unroll
    for (int u = 0; u < 3; ++u) {
        int i0 = ibase + u;
        int i1 = ibase + 3 + u;
        bool k0 = i0 < 365, k1 = i1 < 365;
        cur[u][0] = k0 ? inp0[(long)i0 * PP] : 0.f;
        cur[u][1] = k0 ? inp1[(long)i0 * PP] : 0.f;
        nxt[u][0] = k1 ? inp0[(long)i1 * PP] : 0.f;
        nxt[u][1] = k1 ? inp1[(long)i1 * PP] : 0.f;
    }

    for (int g = 0; g < NG; ++g) {
        float nn[3][2];
#pragma unroll
        for (int u = 0; u < 3; ++u) {
            int i = ibase + 3 * (g + 2) + u;
            bool ok = i < 365;
            nn[u][0] = ok ? inp0[(long)i * PP] : 0.f;
            nn[u][1] = ok ? inp1[(long)i * PP] : 0.f;
        }
#pragma unroll
        for (int u = 0; u < 3; ++u)
            pump12(s1, s2, cur[u], oc, j0, o20, o21);
#pragma unroll
        for (int u = 0; u < 3; ++u) {
            cur[u][0] = nxt[u][0]; cur[u][1] = nxt[u][1];
            nxt[u][0] = nn[u][0];  nxt[u][1] = nn[u][1];
        }
    }
    pump12(s1, s2, cur[0], oc, j0, o20, o21);   // remainder feed

    // zero-tail: stage-1 pooled indices beyond Iend (only j1==37 needs idx 119)
    float z[2][3] = {{0.f, 0.f, 0.f}, {0.f, 0.f, 0.f}};
    float v2[2][3];
    for (int idx = Iend + 1; idx <= 3 * j1 + 8; ++idx) {
        if (feed3(s2, z, v2)) {
            int j = j0 + oc;
            oc++;
#pragma unroll
            for (int co = 0; co < 3; ++co) {
                o20[(long)(co * 37 + j) * PP] = v2[0][co];
                o21[(long)(co * 37 + j) * PP] = v2[1][co];
            }
        }
    }
}

// ---------------------------------------------------------------------------
// Single-stream stage machine (round-7 form) for the small s3+s4 chain.
// ---------------------------------------------------------------------------
template<int CIN>
struct Stage {
    float w[3][CIN][5];
    float b[3];
    float xw[CIN][5];
    float m1[3], m2[3], m3[3];
    int nin;
};

template<int CIN>
__device__ __forceinline__ void stage_reset(Stage<CIN>& s) {
#pragma unroll
    for (int ci = 0; ci < CIN; ++ci)
#pragma unroll
        for (int k = 0; k < 5; ++k) s.xw[ci][k] = 0.f;
#pragma unroll
    for (int co = 0; co < 3; ++co) { s.m1[co] = -1e30f; s.m2[co] = -1e30f; s.m3[co] = -1e30f; }
    s.nin = 0;
}

__device__ __forceinline__ void init_s3(Stage<3>& s, const float* __restrict__ Wt,
                                        const float* __restrict__ Bs, int p) {
    const float* wp = Wt + (long)p * 45;
#pragma unroll
    for (int co = 0; co < 3; ++co)
#pragma unroll
        for (int ci = 0; ci < 3; ++ci)
#pragma unroll
            for (int k = 0; k < 5; ++k)
                s.w[co][ci][k] = wp[(co * 3 + ci) * 5 + k];
#pragma unroll
    for (int co = 0; co < 3; ++co) s.b[co] = Bs[(long)p * 3 + co];
    stage_reset(s);
}

template<int CIN>
__device__ __forceinline__ bool feed(Stage<CIN>& s, const float* in, float* out) {
#pragma unroll
    for (int ci = 0; ci < CIN; ++ci) {
        s.xw[ci][0] = s.xw[ci][1];
        s.xw[ci][1] = s.xw[ci][2];
        s.xw[ci][2] = s.xw[ci][3];
        s.xw[ci][3] = s.xw[ci][4];
        s.xw[ci][4] = in[ci];
    }
    int t = s.nin - 2;
    s.nin++;
    if (t < 0) return false;

    float c[3];
#pragma unroll
    for (int co = 0; co < 3; ++co) {
        float a = s.b[co];
#pragma unroll
        for (int ci = 0; ci < CIN; ++ci)
#pragma unroll
            for (int k = 0; k < 5; ++k)
                a = fmaf(s.xw[ci][k], s.w[co][ci][k], a);
        c[co] = fmaxf(a, 0.f);
    }

    bool emit = false;
    int ph = t % 3;
    if (ph == 0) {
        if (t >= 9) {
#pragma unroll
            for (int co = 0; co < 3; ++co) out[co] = fmaxf(s.m1[co], c[co]);
            emit = true;
        }
#pragma unroll
        for (int co = 0; co < 3; ++co) {
            float a = fmaxf(s.m2[co], c[co]);
            float bb = fmaxf(s.m3[co], c[co]);
            s.m1[co] = a; s.m2[co] = bb; s.m3[co] = c[co];
        }
    } else {
#pragma unroll
        for (int co = 0; co < 3; ++co) {
            s.m1[co] = fmaxf(s.m1[co], c[co]);
            s.m2[co] = fmaxf(s.m2[co], c[co]);
            s.m3[co] = fmaxf(s.m3[co], c[co]);
        }
    }
    return emit;
}

// ---------------------------------------------------------------------------
// Fused stage3+stage4: h2 [256][3][37][399] -> cbuf[b*1297 + co*399 + p]
// ---------------------------------------------------------------------------
__global__ __launch_bounds__(64)
void conv_s34(const float* __restrict__ h2,
              const float* __restrict__ W3, const float* __restrict__ b3,
              const float* __restrict__ W4, const float* __restrict__ b4,
              float* __restrict__ cbuf)
{
    int gid = blockIdx.x * 64 + threadIdx.x;
    if (gid >= BB * PP) return;
    int b = gid / PP;
    int p = gid - b * PP;

    Stage<3> s3, s4;
    init_s3(s3, W3, b3, p);
    init_s3(s4, W4, b4, p);

    const float* inp = h2 + (long)b * (3 * 37 * PP) + p;
    float* o4 = cbuf + (long)b * 1297 + p;

    float v3[3], v4[3];
    float z[3] = {0.f, 0.f, 0.f};

    float cur[3], nxt[3];
#pragma unroll
    for (int ci = 0; ci < 3; ++ci) {
        cur[ci] = inp[(long)(ci * 37 + 0) * PP];
        nxt[ci] = inp[(long)(ci * 37 + 1) * PP];
    }

    for (int i = 0; i < 39; ++i) {              // 37 real + 2 pads
        float nn[3];
        int i2 = i + 2;
#pragma unroll
        for (int ci = 0; ci < 3; ++ci)
            nn[ci] = (i2 < 37) ? inp[(long)(ci * 37 + i2) * PP] : 0.f;
        if (feed(s3, cur, v3)) {
            if (feed(s4, v3, v4)) {
#pragma unroll
                for (int co = 0; co < 3; ++co) o4[co * PP] = v4[co];
            }
        }
        cur[0] = nxt[0]; cur[1] = nxt[1]; cur[2] = nxt[2];
        nxt[0] = nn[0];  nxt[1] = nn[1];  nxt[2] = nn[2];
    }
    for (int r = 0; r < 2; ++r) {               // flush s4
        if (feed(s4, z, v4)) {
#pragma unroll
            for (int co = 0; co < 3; ++co) o4[co * PP] = v4[co];
        }
    }
}

// ---------------------------------------------------------------------------
// Split-K GEMM with f32 atomic accumulation. out pre-seeded with bias.
// ---------------------------------------------------------------------------
template<int RELU_A>
__global__ __launch_bounds__(256)
void gemm_atomic(const float* __restrict__ A,
                 const float* __restrict__ Wt,
                 float* __restrict__ out,
                 int K, int N, int lda, int ldo, int kchunk)
{
    __shared__ float As[32][36];
    __shared__ float Bs[32][36];

    int tid = threadIdx.x;
    int ty  = tid >> 3;
    int tx4 = (tid & 7) * 4;
    int c0 = blockIdx.x * 32;
    int m0 = blockIdx.y * 32;
    int k0 = blockIdx.z * kchunk;
    int klim = min(K, k0 + kchunk);

    float4 acc = make_float4(0.f, 0.f, 0.f, 0.f);

    for (int kb = k0; kb < klim; kb += 32) {
#pragma unroll
        for (int j = 0; j < 4; ++j) {
            int kk = kb + tx4 + j;
            float v = (kk < klim) ? A[(long)(m0 + ty) * lda + kk] : 0.f;
            if (RELU_A) v = fmaxf(v, 0.f);
            As[ty][tx4 + j] = v;
        }
#pragma unroll
        for (int j = 0; j < 4; ++j) {
            int kk = kb + ty;
            int c = c0 + tx4 + j;
            Bs[ty][tx4 + j] = (kk < klim && c < N) ? Wt[(long)kk * N + c] : 0.f;
        }
        __syncthreads();
#pragma unroll
        for (int kk = 0; kk < 32; ++kk) {
            float a = As[ty][kk];
            float4 bv = *(const float4*)&Bs[kk][tx4];
            acc.x = fmaf(a, bv.x, acc.x);
            acc.y = fmaf(a, bv.y, acc.y);
            acc.z = fmaf(a, bv.z, acc.z);
            acc.w = fmaf(a, bv.w, acc.w);
        }
        __syncthreads();
    }

    long m = m0 + ty;
    if (c0 + tx4 + 0 < N) atomicAdd(&out[m * ldo + c0 + tx4 + 0], acc.x);
    if (c0 + tx4 + 1 < N) atomicAdd(&out[m * ldo + c0 + tx4 + 1], acc.y);
    if (c0 + tx4 + 2 < N) atomicAdd(&out[m * ldo + c0 + tx4 + 2], acc.z);
    if (c0 + tx4 + 3 < N) atomicAdd(&out[m * ldo + c0 + tx4 + 3], acc.w);
}

__global__ __launch_bounds__(256)
void init_bias(float* __restrict__ e1, const float* __restrict__ lb1,
               float* __restrict__ e2, const float* __restrict__ lb2,
               float* __restrict__ enc2, const float* __restrict__ lb3,
               float* __restrict__ c1, const float* __restrict__ cb1,
               float* __restrict__ c2, const float* __restrict__ cb2,
               float* __restrict__ c3, const float* __restrict__ cb3)
{
    int idx = blockIdx.x * 256 + threadIdx.x;
    if (idx < BB * 700) { e1[idx] = lb1[idx % 700]; return; }
    idx -= BB * 700;
    if (idx < BB * 200) { e2[idx] = lb2[idx % 200]; return; }
    idx -= BB * 200;
    if (idx < BB * 100) { int m = idx / 100, c = idx % 100; enc2[(long)m * 1297 + c] = lb3[c]; return; }
    idx -= BB * 100;
    if (idx < BB * 500) { c1[idx] = cb1[idx % 500]; return; }
    idx -= BB * 500;
    if (idx < BB * 100) { c2[idx] = cb2[idx % 100]; return; }
    idx -= BB * 100;
    if (idx < BB * 20)  { c3[idx] = cb3[idx % 20]; return; }
}

__global__ __launch_bounds__(64)
void final_kernel(const float* __restrict__ c3,
                  const float* __restrict__ fW,
                  const float* __restrict__ fb,
                  float* __restrict__ out)
{
    int m = blockIdx.x * 64 + threadIdx.x;
    if (m >= BB) return;
    float acc = fb[0];
#pragma unroll
    for (int k = 0; k < 20; ++k)
        acc = fmaf(fmaxf(c3[m * 20 + k], 0.f), fW[k], acc);
    out[m] = acc;
}

extern "C" void kernel_launch(void* const* d_in, const int* in_sizes, int n_in,
                              void* d_out, int out_size, void* d_ws, size_t ws_size,
                              hipStream_t stream)
{
    const float* x   = (const float*)d_in[0];
    const float* x2  = (const float*)d_in[1];
    const float* W1  = (const float*)d_in[2];
    const float* b1  = (const float*)d_in[3];
    const float* W2  = (const float*)d_in[4];
    const float* b2  = (const float*)d_in[5];
    const float* W3  = (const float*)d_in[6];
    const float* b3  = (const float*)d_in[7];
    const float* W4  = (const float*)d_in[8];
    const float* b4  = (const float*)d_in[9];
    const float* lW1 = (const float*)d_in[10];
    const float* lb1 = (const float*)d_in[11];
    const float* lW2 = (const float*)d_in[12];
    const float* lb2 = (const float*)d_in[13];
    const float* lW3 = (const float*)d_in[14];
    const float* lb3 = (const float*)d_in[15];
    const float* cW1 = (const float*)d_in[16];
    const float* cb1 = (const float*)d_in[17];
    const float* cW2 = (const float*)d_in[18];
    const float* cb2 = (const float*)d_in[19];
    const float* cW3 = (const float*)d_in[20];
    const float* cb3 = (const float*)d_in[21];
    const float* fW  = (const float*)d_in[22];
    const float* fb  = (const float*)d_in[23];
    float* out = (float*)d_out;

    float* ws = (float*)d_ws;
    const long n_h2   = (long)BB * 3 * 37 * PP;
    const long n_cbuf = (long)BB * 1297;
    float* h2   = ws;
    float* cbuf = h2 + n_h2;
    float* e1   = cbuf + n_cbuf;
    float* e2   = e1 + (long)BB * 700;
    float* c1   = e2 + (long)BB * 200;
    float* c2   = c1 + (long)BB * 500;
    float* c3b  = c2 + (long)BB * 100;

    init_bias<<<1620, 256, 0, stream>>>(e1, lb1, e2, lb2, cbuf + 1197, lb3,
                                        c1, cb1, c2, cb2, c3b, cb3);

    // fused conv chains: dual-b-stream s1+s2 (798 WGs x 3 segs), s3+s4 single
    conv_s12_seg<<<dim3(798, 3), 64, 0, stream>>>(x, W1, b1, W2, b2, h2);
    conv_s34<<<1596, 64, 0, stream>>>(h2, W3, b3, W4, b4, cbuf);

    // enc2 path (ReLU applied on consumer's A-load)
    gemm_atomic<0><<<dim3(22, 8, 6), 256, 0, stream>>>(x2, lW1, e1, 1307, 700, 1307, 700, 256);
    gemm_atomic<1><<<dim3( 7, 8, 6), 256, 0, stream>>>(e1, lW2, e2,  700, 200,  700, 200, 128);
    gemm_atomic<1><<<dim3( 4, 8, 4), 256, 0, stream>>>(e2, lW3, cbuf + 1197, 200, 100, 200, 1297, 64);

    // combined head
    gemm_atomic<0><<<dim3(16, 8, 6), 256, 0, stream>>>(cbuf, cW1, c1, 1297, 500, 1297, 500, 256);
    gemm_atomic<1><<<dim3( 4, 8, 8), 256, 0, stream>>>(c1, cW2, c2, 500, 100, 500, 100, 64);
    gemm_atomic<1><<<dim3( 1, 8, 4), 256, 0, stream>>>(c2, cW3, c3b, 100, 20, 100, 20, 32);

    final_kernel<<<dim3(4), 64, 0, stream>>>(c3b, fW, fb, out);
}

// Round 10
// 196.809 us; speedup vs baseline: 1.3891x; 1.3891x over previous
//
#include <hip/hip_runtime.h>

#define PP 399
#define BB 256

// ===========================================================================
// Fused stage1+stage2 conv+relu+maxpool, rewritten with group-of-3 pooling:
//   A1_k = max(c1[3k], c1[3k+1], c1[3k+2])
//   e[I] = relu(max(A1_I, A1_{I+1}, A1_{I+2}, c1[3(I+3)]))        (s1 pooled)
//   A2_m = max(c2[3m..3m+2]),  h2[J] = relu(max(A2_J,A2_{J+1},A2_{J+2},c2[3(J+3)]))
// Pipeline per group k: 3 s1-convs -> A1_k ; emit e[k-3] (uses c0 of group k);
// e feeds s2 FIFO; c2[t=k-5]; s2 pool phase p2=(t-3j0)%3 is compile-time per
// unrolled sub-iteration. Segment = template arg (j-ranges {0..13,13..25,25..37}).
// All state arrays statically indexed (rule #20). h2 layout: [B][37][3][PP].
// ===========================================================================

template<int SEG>
__device__ __forceinline__ float xload(const float* __restrict__ inp, int idx) {
    if (SEG == 2) {
        int ic = idx < 364 ? idx : 364;          // clamped addr stays in-bounds
        float v = inp[(long)ic * PP];
        return (idx <= 364) ? v : 0.f;           // uniform condition
    }
    return inp[(long)idx * PP];
}

// one s1 group: convs at taus using xv[OFF..OFF+6]; returns A1 and first conv c0
template<int OFF>
__device__ __forceinline__ void s1_group(const float (&xv)[13],
    const float (&w1)[3][5], const float (&B1)[3],
    float (&A1)[3], float (&c0)[3])
{
#pragma unroll
    for (int co = 0; co < 3; ++co) {
        float a0 = B1[co], a1 = B1[co], a2 = B1[co];
#pragma unroll
        for (int t = 0; t < 5; ++t) {
            a0 = fmaf(xv[OFF + t],     w1[co][t], a0);
            a1 = fmaf(xv[OFF + 1 + t], w1[co][t], a1);
            a2 = fmaf(xv[OFF + 2 + t], w1[co][t], a2);
        }
        c0[co] = a0;
        A1[co] = fmaxf(fmaxf(a0, a1), a2);
    }
}

// s2 step: consume one e (newest), optionally compute c2 and pool/emit.
// Invariant before P2==0 step at s2-group m: A2cur=A2_{m-1}, A2c=A2_{m-2},
// A2b=A2_{m-3}; rotate, then window J=m-3 = max(A2a,A2b,A2c,c2,0).
template<int P2>
__device__ __forceinline__ void s2_step(
    float (&fe)[3][4], const float (&e)[3],
    const float (&w2)[3][3][5], const float (&B2)[3],
    float (&A2a)[3], float (&A2b)[3], float (&A2c)[3], float (&A2cur)[3],
    float*& op, bool do_c2, bool do_emit)
{
    if (do_c2) {
        float c2v[3];
#pragma unroll
        for (int co = 0; co < 3; ++co) {
            float a = B2[co];
#pragma unroll
            for (int ci = 0; ci < 3; ++ci) {
                a = fmaf(fe[ci][0], w2[co][ci][0], a);
                a = fmaf(fe[ci][1], w2[co][ci][1], a);
                a = fmaf(fe[ci][2], w2[co][ci][2], a);
                a = fmaf(fe[ci][3], w2[co][ci][3], a);
                a = fmaf(e[ci],     w2[co][ci][4], a);
            }
            c2v[co] = a;
        }
        if (P2 == 0) {
#pragma unroll
            for (int co = 0; co < 3; ++co) { A2a[co] = A2b[co]; A2b[co] = A2c[co]; A2c[co] = A2cur[co]; }
            if (do_emit) {
#pragma unroll
                for (int co = 0; co < 3; ++co)
                    op[co * PP] = fmaxf(fmaxf(fmaxf(fmaxf(A2a[co], A2b[co]), A2c[co]), c2v[co]), 0.f);
                op += 3 * PP;
            }
#pragma unroll
            for (int co = 0; co < 3; ++co) A2cur[co] = c2v[co];
        } else {
#pragma unroll
            for (int co = 0; co < 3; ++co) A2cur[co] = fmaxf(A2cur[co], c2v[co]);
        }
    }
    // FIFO shift (e inserted)
#pragma unroll
    for (int ci = 0; ci < 3; ++ci) {
        fe[ci][0] = fe[ci][1]; fe[ci][1] = fe[ci][2]; fe[ci][2] = fe[ci][3]; fe[ci][3] = e[ci];
    }
}

template<int P2>
__device__ __forceinline__ void emit_e(
    const float (&Aa)[3], const float (&Ab)[3], const float (&Ac)[3],
    const float (&c0)[3],
    float (&fe)[3][4],
    const float (&w2)[3][3][5], const float (&B2)[3],
    float (&A2a)[3], float (&A2b)[3], float (&A2c)[3], float (&A2cur)[3],
    float*& op, bool do_c2, bool do_emit)
{
    float e[3];
#pragma unroll
    for (int co = 0; co < 3; ++co)
        e[co] = fmaxf(fmaxf(fmaxf(fmaxf(Aa[co], Ab[co]), Ac[co]), c0[co]), 0.f);
    s2_step<P2>(fe, e, w2, B2, A2a, A2b, A2c, A2cur, op, do_c2, do_emit);
}

template<int SEG>
__device__ __forceinline__ void s12_body(
    const float* __restrict__ x,
    const float* __restrict__ W1, const float* __restrict__ b1,
    const float* __restrict__ W2, const float* __restrict__ b2,
    float* __restrict__ h2, int b, int p)
{
    constexpr int j0 = (SEG == 0) ? 0 : (SEG == 1) ? 13 : 25;
    constexpr int j1 = (SEG == 0) ? 13 : (SEG == 1) ? 25 : 37;
    constexpr int k0 = (SEG == 0) ? 0 : 3 * j0 - 2;                 // 0, 37, 73
    constexpr int kend = (3 * j1 + 11 < 121) ? (3 * j1 + 11) : 121; // 50, 86, 121
    constexpr int NGRP = kend - k0 + 1;                             // 51, 50, 49
    constexpr int NS = NGRP / 3;                                    // 17, 16, 16
    constexpr int NREM = NGRP - 3 * NS;                             // 0, 2, 1
    constexpr int c2start = (SEG == 0) ? 5 : (k0 + 7);              // 5, 44, 80
    constexpr int e2start = 3 * j0 + 14;                            // 14, 53, 89
    constexpr int P2_0 = (SEG == 0) ? 1 : 2;   // p2 phase of sub-iteration u
    constexpr int P2_1 = (SEG == 0) ? 2 : 0;
    constexpr int P2_2 = (SEG == 0) ? 0 : 1;

    float w1[3][5], B1[3];
    {
        const float* wp = W1 + (long)p * 15;
#pragma unroll
        for (int co = 0; co < 3; ++co) {
#pragma unroll
            for (int t = 0; t < 5; ++t) w1[co][t] = wp[co * 5 + t];
            B1[co] = b1[(long)p * 3 + co];
        }
    }
    float w2[3][3][5], B2[3];
    {
        const float* wp = W2 + (long)p * 45;
#pragma unroll
        for (int co = 0; co < 3; ++co) {
#pragma unroll
            for (int ci = 0; ci < 3; ++ci)
#pragma unroll
                for (int t = 0; t < 5; ++t) w2[co][ci][t] = wp[(co * 3 + ci) * 5 + t];
            B2[co] = b2[(long)p * 3 + co];
        }
    }

    const float* __restrict__ inp = x + (long)b * 365 * PP + p;
    float* op = h2 + ((long)b * 37 + j0) * 3 * PP + p;   // layout [B][37][3][PP]

    // x window regs: xv[s] = x[3k-2+s], covering x[3k-2 .. 3k+10]
    float xv[13];
#pragma unroll
    for (int s = 0; s < 13; ++s) {
        int idx = 3 * k0 - 2 + s;          // SEG0: s<2 -> pad 0 (folds)
        xv[s] = (idx >= 0) ? inp[(long)idx * PP] : 0.f;
    }

    float fe[3][4];                        // e-FIFO (e[t-2..t+1]); init = left pad
    float A1p[3][3];                       // prev super's A1 (groups k-3,k-2,k-1)
    float A2a[3], A2b[3], A2c[3], A2cur[3];
#pragma unroll
    for (int co = 0; co < 3; ++co) {
        fe[0][co < 3 ? 0 : 0] = 0.f; // placate unroll; real init below
    }
#pragma unroll
    for (int ci = 0; ci < 3; ++ci)
#pragma unroll
        for (int s = 0; s < 4; ++s) fe[ci][s] = 0.f;
#pragma unroll
    for (int co = 0; co < 3; ++co) {
        A1p[0][co] = 0.f; A1p[1][co] = 0.f; A1p[2][co] = 0.f;
        A2a[co] = 0.f; A2b[co] = 0.f; A2c[co] = 0.f; A2cur[co] = 0.f;
    }

    for (int S = 0; S < NS; ++S) {
        int k = k0 + 3 * S;
        // prefetch next super's 9 x-values (x[3k+11 .. 3k+19])
        float q[9];
#pragma unroll
        for (int s = 0; s < 9; ++s)
            q[s] = xload<SEG>(inp, 3 * k + 11 + s);

        float A1c0[3], A1c1[3], A1c2[3], c0[3];

        // ---- u = 0 (group k) ----
        s1_group<0>(xv, w1, B1, A1c0, c0);
        if (S >= 1)
            emit_e<P2_0>(A1p[0], A1p[1], A1p[2], c0, fe, w2, B2,
                         A2a, A2b, A2c, A2cur, op,
                         k >= c2start, k >= e2start);
        // ---- u = 1 (group k+1) ----
        s1_group<3>(xv, w1, B1, A1c1, c0);
        if (S >= 1)
            emit_e<P2_1>(A1p[1], A1p[2], A1c0, c0, fe, w2, B2,
                         A2a, A2b, A2c, A2cur, op,
                         k + 1 >= c2start, k + 1 >= e2start);
        // ---- u = 2 (group k+2) ----
        s1_group<6>(xv, w1, B1, A1c2, c0);
        if (S >= 1)
            emit_e<P2_2>(A1p[2], A1c0, A1c1, c0, fe, w2, B2,
                         A2a, A2b, A2c, A2cur, op,
                         k + 2 >= c2start, k + 2 >= e2start);

        // latch
#pragma unroll
        for (int co = 0; co < 3; ++co) {
            A1p[0][co] = A1c0[co]; A1p[1][co] = A1c1[co]; A1p[2][co] = A1c2[co];
        }
        xv[0] = xv[9]; xv[1] = xv[10]; xv[2] = xv[11]; xv[3] = xv[12];
#pragma unroll
        for (int s = 0; s < 9; ++s) xv[4 + s] = q[s];
    }

    // remainder groups (phases continue: u = 0, then 1)
    if constexpr (NREM >= 1) {
        int k = k0 + 3 * NS;
        float A1c0[3], c0[3];
        s1_group<0>(xv, w1, B1, A1c0, c0);
        emit_e<P2_0>(A1p[0], A1p[1], A1p[2], c0, fe, w2, B2,
                     A2a, A2b, A2c, A2cur, op,
                     k >= c2start, k >= e2start);
        if constexpr (NREM >= 2) {
            float A1c1[3];
            s1_group<3>(xv, w1, B1, A1c1, c0);
            emit_e<P2_1>(A1p[1], A1p[2], A1c0, c0, fe, w2, B2,
                         A2a, A2b, A2c, A2cur, op,
                         k + 1 >= c2start, k + 1 >= e2start);
        }
    }
    // SEG2 tail: one zero-e feed (e[119]) -> c2[117] -> emit window J=36
    if constexpr (SEG == 2) {
        float ez[3] = {0.f, 0.f, 0.f};
        s2_step<0>(fe, ez, w2, B2, A2a, A2b, A2c, A2cur, op, true, true);
    }
}

__global__ __launch_bounds__(64)
void conv_s12(const float* __restrict__ x,
              const float* __restrict__ W1, const float* __restrict__ b1,
              const float* __restrict__ W2, const float* __restrict__ b2,
              float* __restrict__ h2)
{
    int gid = blockIdx.x * 64 + threadIdx.x;
    if (gid >= BB * PP) return;
    int b = gid / PP;
    int p = gid - b * PP;
    if (blockIdx.y == 0)      s12_body<0>(x, W1, b1, W2, b2, h2, b, p);
    else if (blockIdx.y == 1) s12_body<1>(x, W1, b1, W2, b2, h2, b, p);
    else                      s12_body<2>(x, W1, b1, W2, b2, h2, b, p);
}

// ---------------------------------------------------------------------------
// Single-stream stage machine (R7 form) for the small s3+s4 chain.
// ---------------------------------------------------------------------------
template<int CIN>
struct Stage {
    float w[3][CIN][5];
    float b[3];
    float xw[CIN][5];
    float m1[3], m2[3], m3[3];
    int nin;
};

__device__ __forceinline__ void init_s3(Stage<3>& s, const float* __restrict__ Wt,
                                        const float* __restrict__ Bs, int p) {
    const float* wp = Wt + (long)p * 45;
#pragma unroll
    for (int co = 0; co < 3; ++co)
#pragma unroll
        for (int ci = 0; ci < 3; ++ci)
#pragma unroll
            for (int k = 0; k < 5; ++k)
                s.w[co][ci][k] = wp[(co * 3 + ci) * 5 + k];
#pragma unroll
    for (int co = 0; co < 3; ++co) s.b[co] = Bs[(long)p * 3 + co];
#pragma unroll
    for (int ci = 0; ci < 3; ++ci)
#pragma unroll
        for (int k = 0; k < 5; ++k) s.xw[ci][k] = 0.f;
#pragma unroll
    for (int co = 0; co < 3; ++co) { s.m1[co] = -1e30f; s.m2[co] = -1e30f; s.m3[co] = -1e30f; }
    s.nin = 0;
}

template<int CIN>
__device__ __forceinline__ bool feed(Stage<CIN>& s, const float* in, float* out) {
#pragma unroll
    for (int ci = 0; ci < CIN; ++ci) {
        s.xw[ci][0] = s.xw[ci][1];
        s.xw[ci][1] = s.xw[ci][2];
        s.xw[ci][2] = s.xw[ci][3];
        s.xw[ci][3] = s.xw[ci][4];
        s.xw[ci][4] = in[ci];
    }
    int t = s.nin - 2;
    s.nin++;
    if (t < 0) return false;

    float c[3];
#pragma unroll
    for (int co = 0; co < 3; ++co) {
        float a = s.b[co];
#pragma unroll
        for (int ci = 0; ci < CIN; ++ci)
#pragma unroll
            for (int k = 0; k < 5; ++k)
                a = fmaf(s.xw[ci][k], s.w[co][ci][k], a);
        c[co] = fmaxf(a, 0.f);
    }

    bool emit = false;
    int ph = t % 3;
    if (ph == 0) {
        if (t >= 9) {
#pragma unroll
            for (int co = 0; co < 3; ++co) out[co] = fmaxf(s.m1[co], c[co]);
            emit = true;
        }
#pragma unroll
        for (int co = 0; co < 3; ++co) {
            float a = fmaxf(s.m2[co], c[co]);
            float bb = fmaxf(s.m3[co], c[co]);
            s.m1[co] = a; s.m2[co] = bb; s.m3[co] = c[co];
        }
    } else {
#pragma unroll
        for (int co = 0; co < 3; ++co) {
            s.m1[co] = fmaxf(s.m1[co], c[co]);
            s.m2[co] = fmaxf(s.m2[co], c[co]);
            s.m3[co] = fmaxf(s.m3[co], c[co]);
        }
    }
    return emit;
}

// h2 [B][37][3][PP] -> cbuf[b*1297 + co*399 + p]
__global__ __launch_bounds__(64)
void conv_s34(const float* __restrict__ h2,
              const float* __restrict__ W3, const float* __restrict__ b3,
              const float* __restrict__ W4, const float* __restrict__ b4,
              float* __restrict__ cbuf)
{
    int gid = blockIdx.x * 64 + threadIdx.x;
    if (gid >= BB * PP) return;
    int b = gid / PP;
    int p = gid - b * PP;

    Stage<3> s3, s4;
    init_s3(s3, W3, b3, p);
    init_s3(s4, W4, b4, p);

    const float* inp = h2 + (long)b * 37 * 3 * PP + p;
    float* o4 = cbuf + (long)b * 1297 + p;

    float v3[3], v4[3];
    float z[3] = {0.f, 0.f, 0.f};

    float cur[3], nxt[3];
#pragma unroll
    for (int ci = 0; ci < 3; ++ci) {
        cur[ci] = inp[(long)(0 * 3 + ci) * PP];
        nxt[ci] = inp[(long)(1 * 3 + ci) * PP];
    }

    for (int i = 0; i < 39; ++i) {              // 37 real + 2 pads
        float nn[3];
        int i2 = i + 2;
#pragma unroll
        for (int ci = 0; ci < 3; ++ci)
            nn[ci] = (i2 < 37) ? inp[(long)(i2 * 3 + ci) * PP] : 0.f;
        if (feed(s3, cur, v3)) {
            if (feed(s4, v3, v4)) {
#pragma unroll
                for (int co = 0; co < 3; ++co) o4[co * PP] = v4[co];
            }
        }
        cur[0] = nxt[0]; cur[1] = nxt[1]; cur[2] = nxt[2];
        nxt[0] = nn[0];  nxt[1] = nn[1];  nxt[2] = nn[2];
    }
    for (int r = 0; r < 2; ++r) {               // flush s4
        if (feed(s4, z, v4)) {
#pragma unroll
            for (int co = 0; co < 3; ++co) o4[co * PP] = v4[co];
        }
    }
}

// ---------------------------------------------------------------------------
// Split-K GEMM with f32 atomic accumulation. out pre-seeded with bias.
// ---------------------------------------------------------------------------
template<int RELU_A>
__global__ __launch_bounds__(256)
void gemm_atomic(const float* __restrict__ A,
                 const float* __restrict__ Wt,
                 float* __restrict__ out,
                 int K, int N, int lda, int ldo, int kchunk)
{
    __shared__ float As[32][36];
    __shared__ float Bs[32][36];

    int tid = threadIdx.x;
    int ty  = tid >> 3;
    int tx4 = (tid & 7) * 4;
    int c0 = blockIdx.x * 32;
    int m0 = blockIdx.y * 32;
    int k0 = blockIdx.z * kchunk;
    int klim = min(K, k0 + kchunk);

    float4 acc = make_float4(0.f, 0.f, 0.f, 0.f);

    for (int kb = k0; kb < klim; kb += 32) {
#pragma unroll
        for (int j = 0; j < 4; ++j) {
            int kk = kb + tx4 + j;
            float v = (kk < klim) ? A[(long)(m0 + ty) * lda + kk] : 0.f;
            if (RELU_A) v = fmaxf(v, 0.f);
            As[ty][tx4 + j] = v;
        }
#pragma unroll
        for (int j = 0; j < 4; ++j) {
            int kk = kb + ty;
            int c = c0 + tx4 + j;
            Bs[ty][tx4 + j] = (kk < klim && c < N) ? Wt[(long)kk * N + c] : 0.f;
        }
        __syncthreads();
#pragma unroll
        for (int kk = 0; kk < 32; ++kk) {
            float a = As[ty][kk];
            float4 bv = *(const float4*)&Bs[kk][tx4];
            acc.x = fmaf(a, bv.x, acc.x);
            acc.y = fmaf(a, bv.y, acc.y);
            acc.z = fmaf(a, bv.z, acc.z);
            acc.w = fmaf(a, bv.w, acc.w);
        }
        __syncthreads();
    }

    long m = m0 + ty;
    if (c0 + tx4 + 0 < N) atomicAdd(&out[m * ldo + c0 + tx4 + 0], acc.x);
    if (c0 + tx4 + 1 < N) atomicAdd(&out[m * ldo + c0 + tx4 + 1], acc.y);
    if (c0 + tx4 + 2 < N) atomicAdd(&out[m * ldo + c0 + tx4 + 2], acc.z);
    if (c0 + tx4 + 3 < N) atomicAdd(&out[m * ldo + c0 + tx4 + 3], acc.w);
}

__global__ __launch_bounds__(256)
void init_bias(float* __restrict__ e1, const float* __restrict__ lb1,
               float* __restrict__ e2, const float* __restrict__ lb2,
               float* __restrict__ enc2, const float* __restrict__ lb3,
               float* __restrict__ c1, const float* __restrict__ cb1,
               float* __restrict__ c2, const float* __restrict__ cb2,
               float* __restrict__ c3, const float* __restrict__ cb3)
{
    int idx = blockIdx.x * 256 + threadIdx.x;
    if (idx < BB * 700) { e1[idx] = lb1[idx % 700]; return; }
    idx -= BB * 700;
    if (idx < BB * 200) { e2[idx] = lb2[idx % 200]; return; }
    idx -= BB * 200;
    if (idx < BB * 100) { int m = idx / 100, c = idx % 100; enc2[(long)m * 1297 + c] = lb3[c]; return; }
    idx -= BB * 100;
    if (idx < BB * 500) { c1[idx] = cb1[idx % 500]; return; }
    idx -= BB * 500;
    if (idx < BB * 100) { c2[idx] = cb2[idx % 100]; return; }
    idx -= BB * 100;
    if (idx < BB * 20)  { c3[idx] = cb3[idx % 20]; return; }
}

__global__ __launch_bounds__(64)
void final_kernel(const float* __restrict__ c3,
                  const float* __restrict__ fW,
                  const float* __restrict__ fb,
                  float* __restrict__ out)
{
    int m = blockIdx.x * 64 + threadIdx.x;
    if (m >= BB) return;
    float acc = fb[0];
#pragma unroll
    for (int k = 0; k < 20; ++k)
        acc = fmaf(fmaxf(c3[m * 20 + k], 0.f), fW[k], acc);
    out[m] = acc;
}

extern "C" void kernel_launch(void* const* d_in, const int* in_sizes, int n_in,
                              void* d_out, int out_size, void* d_ws, size_t ws_size,
                              hipStream_t stream)
{
    const float* x   = (const float*)d_in[0];
    const float* x2  = (const float*)d_in[1];
    const float* W1  = (const float*)d_in[2];
    const float* b1  = (const float*)d_in[3];
    const float* W2  = (const float*)d_in[4];
    const float* b2  = (const float*)d_in[5];
    const float* W3  = (const float*)d_in[6];
    const float* b3  = (const float*)d_in[7];
    const float* W4  = (const float*)d_in[8];
    const float* b4  = (const float*)d_in[9];
    const float* lW1 = (const float*)d_in[10];
    const float* lb1 = (const float*)d_in[11];
    const float* lW2 = (const float*)d_in[12];
    const float* lb2 = (const float*)d_in[13];
    const float* lW3 = (const float*)d_in[14];
    const float* lb3 = (const float*)d_in[15];
    const float* cW1 = (const float*)d_in[16];
    const float* cb1 = (const float*)d_in[17];
    const float* cW2 = (const float*)d_in[18];
    const float* cb2 = (const float*)d_in[19];
    const float* cW3 = (const float*)d_in[20];
    const float* cb3 = (const float*)d_in[21];
    const float* fW  = (const float*)d_in[22];
    const float* fb  = (const float*)d_in[23];
    float* out = (float*)d_out;

    float* ws = (float*)d_ws;
    const long n_h2   = (long)BB * 37 * 3 * PP;
    const long n_cbuf = (long)BB * 1297;
    float* h2   = ws;
    float* cbuf = h2 + n_h2;
    float* e1   = cbuf + n_cbuf;
    float* e2   = e1 + (long)BB * 700;
    float* c1   = e2 + (long)BB * 200;
    float* c2   = c1 + (long)BB * 500;
    float* c3b  = c2 + (long)BB * 100;

    init_bias<<<1620, 256, 0, stream>>>(e1, lb1, e2, lb2, cbuf + 1197, lb3,
                                        c1, cb1, c2, cb2, c3b, cb3);

    // fused conv chains: one dispatch, 3 segments via blockIdx.y
    conv_s12<<<dim3(1596, 3), 64, 0, stream>>>(x, W1, b1, W2, b2, h2);
    conv_s34<<<1596, 64, 0, stream>>>(h2, W3, b3, W4, b4, cbuf);

    // enc2 path (ReLU applied on consumer's A-load)
    gemm_atomic<0><<<dim3(22, 8, 6), 256, 0, stream>>>(x2, lW1, e1, 1307, 700, 1307, 700, 256);
    gemm_atomic<1><<<dim3( 7, 8, 6), 256, 0, stream>>>(e1, lW2, e2,  700, 200,  700, 200, 128);
    gemm_atomic<1><<<dim3( 4, 8, 4), 256, 0, stream>>>(e2, lW3, cbuf + 1197, 200, 100, 200, 1297, 64);

    // combined head
    gemm_atomic<0><<<dim3(16, 8, 6), 256, 0, stream>>>(cbuf, cW1, c1, 1297, 500, 1297, 500, 256);
    gemm_atomic<1><<<dim3( 4, 8, 8), 256, 0, stream>>>(c1, cW2, c2, 500, 100, 500, 100, 64);
    gemm_atomic<1><<<dim3( 1, 8, 4), 256, 0, stream>>>(c2, cW3, c3b, 100, 20, 100, 20, 32);

    final_kernel<<<dim3(4), 64, 0, stream>>>(c3b, fW, fb, out);
}